// Round 1
// baseline (731.972 us; speedup 1.0000x reference)
//
#include <hip/hip_runtime.h>
#include <cstdint>
#include <cstddef>

// ---------------------------------------------------------------------------
// Mamba2 layer forward for B=4, L=2048, d_model=512, d_inner=1024, d_state=128,
// nheads=1, headdim=1024, d_conv=4, ngroups=1.
// Pipeline: cast -> GEMM1(bf16 MFMA) -> dt(f32) -> conv+silu -> chunked scan
//           (S1 local, S2 combine, S3 final+y) -> gate+RMSNorm -> GEMM2 -> out
// ---------------------------------------------------------------------------

typedef __bf16 bf16_t;
typedef __bf16 bf16x8 __attribute__((ext_vector_type(8)));
typedef __bf16 bf16x4 __attribute__((ext_vector_type(4)));
typedef float  f32x4  __attribute__((ext_vector_type(4)));

#define BATCH   4
#define SEQLEN  2048
#define MROWS   8192          // B*L
#define DMODEL  512
#define DINNER  1024
#define DSTATE  128
#define NZX     2304          // z(1024) + xBC(1280); dt col handled separately
#define NCONV   1280
#define CHUNK   128           // scan chunk length
#define NCHUNK  16            // SEQLEN / CHUNK

__device__ __forceinline__ float siluf(float x) { return x / (1.f + __expf(-x)); }

// ---------------------------------------------------------------------------
// f32 -> bf16 cast (vectorized), n4 = number of float4 groups
// ---------------------------------------------------------------------------
__global__ __launch_bounds__(256) void cast_bf16_kernel(
    const float* __restrict__ in, bf16_t* __restrict__ out, int n4)
{
    int i = blockIdx.x * 256 + threadIdx.x;
    if (i < n4) {
        float4 v = reinterpret_cast<const float4*>(in)[i];
        bf16x4 o;
        o[0] = (bf16_t)v.x; o[1] = (bf16_t)v.y; o[2] = (bf16_t)v.z; o[3] = (bf16_t)v.w;
        reinterpret_cast<bf16x4*>(out)[i] = o;
    }
}

// ---------------------------------------------------------------------------
// bf16 MFMA GEMM: C[M,N] = A[M,K] * B[N,K]^T   (both row-major, K contiguous)
// 128x128 tile, BK=64, 256 threads (4 waves in 2x2 of 64x64), 16x16x32 mfma.
// ---------------------------------------------------------------------------
template <typename OutT>
__global__ __launch_bounds__(256) void gemm_bf16_kernel(
    const bf16_t* __restrict__ A, const bf16_t* __restrict__ B,
    OutT* __restrict__ C, int M, int N, int K)
{
    constexpr int LDT = 72;   // 64 + 8 pad (keeps 16B alignment, spreads banks)
    __shared__ __align__(16) bf16_t As[128 * LDT];
    __shared__ __align__(16) bf16_t Bs[128 * LDT];

    const int bn = blockIdx.x, bm = blockIdx.y;
    const int tid  = threadIdx.x;
    const int wave = tid >> 6, lane = tid & 63;
    const int lr = lane & 15, q = lane >> 4;
    const int wm = (wave & 1) * 64, wn = (wave >> 1) * 64;

    f32x4 acc[4][4];
    #pragma unroll
    for (int i = 0; i < 4; ++i)
        #pragma unroll
        for (int j = 0; j < 4; ++j)
            acc[i][j] = (f32x4){0.f, 0.f, 0.f, 0.f};

    const int row_a0 = bm * 128, row_b0 = bn * 128;
    const int srow = tid >> 3, skc = tid & 7;   // staging: 16B chunk per thread

    for (int kt = 0; kt < K; kt += 64) {
        #pragma unroll
        for (int i = 0; i < 4; ++i) {
            int row = srow + i * 32;
            bf16x8 av = *reinterpret_cast<const bf16x8*>(
                &A[(size_t)(row_a0 + row) * K + kt + skc * 8]);
            *reinterpret_cast<bf16x8*>(&As[row * LDT + skc * 8]) = av;
            bf16x8 bv = *reinterpret_cast<const bf16x8*>(
                &B[(size_t)(row_b0 + row) * K + kt + skc * 8]);
            *reinterpret_cast<bf16x8*>(&Bs[row * LDT + skc * 8]) = bv;
        }
        __syncthreads();
        #pragma unroll
        for (int k0 = 0; k0 < 64; k0 += 32) {
            bf16x8 af[4], bfr[4];
            #pragma unroll
            for (int mi = 0; mi < 4; ++mi)
                af[mi] = *reinterpret_cast<const bf16x8*>(
                    &As[(wm + mi * 16 + lr) * LDT + k0 + q * 8]);
            #pragma unroll
            for (int ni = 0; ni < 4; ++ni)
                bfr[ni] = *reinterpret_cast<const bf16x8*>(
                    &Bs[(wn + ni * 16 + lr) * LDT + k0 + q * 8]);
            #pragma unroll
            for (int mi = 0; mi < 4; ++mi)
                #pragma unroll
                for (int ni = 0; ni < 4; ++ni)
                    acc[mi][ni] = __builtin_amdgcn_mfma_f32_16x16x32_bf16(
                        af[mi], bfr[ni], acc[mi][ni], 0, 0, 0);
        }
        __syncthreads();
    }

    // C/D layout (verified m89/m91): col = lane&15, row = (lane>>4)*4 + reg
    #pragma unroll
    for (int mi = 0; mi < 4; ++mi)
        #pragma unroll
        for (int ni = 0; ni < 4; ++ni)
            #pragma unroll
            for (int ri = 0; ri < 4; ++ri) {
                int row = row_a0 + wm + mi * 16 + q * 4 + ri;
                int col = row_b0 + wn + ni * 16 + lr;
                C[(size_t)row * N + col] = (OutT)acc[mi][ni][ri];
            }
}

// ---------------------------------------------------------------------------
// dt column: dt_raw[r] = dot(x[r,:], W_in[2304,:]) ; dt = softplus(dt_raw+bias)
// dA = exp(dt * A), A = -exp(A_log). One wave per row, fp32 exact.
// ---------------------------------------------------------------------------
__global__ __launch_bounds__(256) void dt_kernel(
    const float* __restrict__ x, const float* __restrict__ W_in,
    const float* __restrict__ dt_bias, const float* __restrict__ A_log,
    float* __restrict__ dtv, float* __restrict__ dAv)
{
    int wave = threadIdx.x >> 6, lane = threadIdx.x & 63;
    int r = blockIdx.x * 4 + wave;
    const float* xr = x + (size_t)r * DMODEL + lane * 8;
    const float* wr = W_in + (size_t)NZX * DMODEL + lane * 8;
    float4 a0 = *reinterpret_cast<const float4*>(xr);
    float4 a1 = *reinterpret_cast<const float4*>(xr + 4);
    float4 b0 = *reinterpret_cast<const float4*>(wr);
    float4 b1 = *reinterpret_cast<const float4*>(wr + 4);
    float s = a0.x * b0.x + a0.y * b0.y + a0.z * b0.z + a0.w * b0.w
            + a1.x * b1.x + a1.y * b1.y + a1.z * b1.z + a1.w * b1.w;
    #pragma unroll
    for (int m = 32; m >= 1; m >>= 1) s += __shfl_xor(s, m);
    if (lane == 0) {
        float t  = s + dt_bias[0];
        float sp = (t > 20.f) ? t : log1pf(expf(t));
        float A  = -expf(A_log[0]);
        dtv[r] = sp;
        dAv[r] = expf(sp * A);
    }
}

// ---------------------------------------------------------------------------
// Causal depthwise conv1d (width 4) + bias + silu over 1280 channels.
// Input: zxbcdt bf16 (stride NZX), channels at col offset 1024. Output f32.
// ---------------------------------------------------------------------------
__global__ __launch_bounds__(256) void conv_kernel(
    const bf16_t* __restrict__ zx, const float* __restrict__ cw,
    const float* __restrict__ cb, float* __restrict__ xconv)
{
    int flat = blockIdx.x * 256 + threadIdx.x;   // MROWS * 320
    int c4 = flat % (NCONV / 4);
    int r  = flat / (NCONV / 4);
    int l  = r & (SEQLEN - 1);
    int ch = c4 * 4;

    float4 w0 = *reinterpret_cast<const float4*>(cw + (size_t)(ch + 0) * 4);
    float4 w1 = *reinterpret_cast<const float4*>(cw + (size_t)(ch + 1) * 4);
    float4 w2 = *reinterpret_cast<const float4*>(cw + (size_t)(ch + 2) * 4);
    float4 w3 = *reinterpret_cast<const float4*>(cw + (size_t)(ch + 3) * 4);
    float w0a[4] = {w0.x, w0.y, w0.z, w0.w};
    float w1a[4] = {w1.x, w1.y, w1.z, w1.w};
    float w2a[4] = {w2.x, w2.y, w2.z, w2.w};
    float w3a[4] = {w3.x, w3.y, w3.z, w3.w};

    float4 bias = *reinterpret_cast<const float4*>(cb + ch);
    float a0 = bias.x, a1 = bias.y, a2 = bias.z, a3 = bias.w;

    #pragma unroll
    for (int k = 0; k < 4; ++k) {
        if (l + k >= 3) {
            bf16x4 v = *reinterpret_cast<const bf16x4*>(
                zx + (size_t)(r + k - 3) * NZX + DINNER + ch);
            a0 += w0a[k] * (float)v[0];
            a1 += w1a[k] * (float)v[1];
            a2 += w2a[k] * (float)v[2];
            a3 += w3a[k] * (float)v[3];
        }
    }
    float4 out;
    out.x = siluf(a0); out.y = siluf(a1); out.z = siluf(a2); out.w = siluf(a3);
    *reinterpret_cast<float4*>(xconv + (size_t)r * NCONV + ch) = out;
}

// ---------------------------------------------------------------------------
// Chunk decay products: chp[b*16+c] = prod_{t in chunk} dA
// ---------------------------------------------------------------------------
__global__ void chunk_prod_kernel(const float* __restrict__ dAv, float* __restrict__ chp)
{
    int t = threadIdx.x;          // 64 = B * NCHUNK
    int b = t >> 4, c = t & 15;
    float v = 1.f;
    for (int i = 0; i < CHUNK; ++i) v *= dAv[b * SEQLEN + c * CHUNK + i];
    chp[t] = v;
}

// ---------------------------------------------------------------------------
// S1: per-chunk local state from zero.  Thread owns one p, state[128] in VGPRs.
// cstate layout: (b, c, n, p)
// ---------------------------------------------------------------------------
__global__ __launch_bounds__(256) void scan_local_kernel(
    const float* __restrict__ xconv, const float* __restrict__ dAv,
    const float* __restrict__ dtv, float* __restrict__ cstate)
{
    int blk = blockIdx.x;               // B * NCHUNK * 4 = 256
    int b  = blk >> 6;
    int c  = (blk >> 2) & 15;
    int pq = blk & 3;
    int p  = pq * 256 + threadIdx.x;

    float st[DSTATE];
    #pragma unroll
    for (int n = 0; n < DSTATE; ++n) st[n] = 0.f;

    int r0 = b * SEQLEN + c * CHUNK;
    for (int tl = 0; tl < CHUNK; ++tl) {
        int r = r0 + tl;
        float dA = dAv[r];
        float dt = dtv[r];
        float xv = xconv[(size_t)r * NCONV + p];
        float coef = dt * xv;
        const float4* Bp = reinterpret_cast<const float4*>(
            xconv + (size_t)r * NCONV + DINNER);
        #pragma unroll
        for (int n4 = 0; n4 < 32; ++n4) {
            float4 bv = Bp[n4];
            st[n4 * 4 + 0] = dA * st[n4 * 4 + 0] + coef * bv.x;
            st[n4 * 4 + 1] = dA * st[n4 * 4 + 1] + coef * bv.y;
            st[n4 * 4 + 2] = dA * st[n4 * 4 + 2] + coef * bv.z;
            st[n4 * 4 + 3] = dA * st[n4 * 4 + 3] + coef * bv.w;
        }
    }
    size_t base = ((size_t)(b * NCHUNK + c) << 17) + p;   // (b,c)*131072 + n*1024 + p
    #pragma unroll
    for (int n = 0; n < DSTATE; ++n) cstate[base + (size_t)n * 1024] = st[n];
}

// ---------------------------------------------------------------------------
// S2: sequential combine across chunks; converts local final states into
// chunk-initial states (in place).
// ---------------------------------------------------------------------------
__global__ __launch_bounds__(256) void scan_combine_kernel(
    float* __restrict__ cstate, const float* __restrict__ chp)
{
    int idx = blockIdx.x * 256 + threadIdx.x;   // B * 131072
    int b   = idx >> 17;
    int np  = idx & 131071;
    float v = 0.f;
    for (int c = 0; c < NCHUNK; ++c) {
        size_t off = ((size_t)(b * NCHUNK + c) << 17) + np;
        float tmp = cstate[off];
        cstate[off] = v;
        v = chp[b * NCHUNK + c] * v + tmp;
    }
}

// ---------------------------------------------------------------------------
// S3: replay chunk from its initial state, emit y[r,p] = state . C_t + Dp*x
// ---------------------------------------------------------------------------
__global__ __launch_bounds__(256) void scan_final_kernel(
    const float* __restrict__ xconv, const float* __restrict__ cstate,
    const float* __restrict__ dAv, const float* __restrict__ dtv,
    const float* __restrict__ Dp, float* __restrict__ yf)
{
    int blk = blockIdx.x;
    int b  = blk >> 6;
    int c  = (blk >> 2) & 15;
    int pq = blk & 3;
    int p  = pq * 256 + threadIdx.x;

    float st[DSTATE];
    size_t base = ((size_t)(b * NCHUNK + c) << 17) + p;
    #pragma unroll
    for (int n = 0; n < DSTATE; ++n) st[n] = cstate[base + (size_t)n * 1024];

    float D0 = Dp[0];
    int r0 = b * SEQLEN + c * CHUNK;
    for (int tl = 0; tl < CHUNK; ++tl) {
        int r = r0 + tl;
        float dA = dAv[r];
        float dt = dtv[r];
        float xv = xconv[(size_t)r * NCONV + p];
        float coef = dt * xv;
        const float4* Bp = reinterpret_cast<const float4*>(
            xconv + (size_t)r * NCONV + DINNER);
        const float4* Cp = reinterpret_cast<const float4*>(
            xconv + (size_t)r * NCONV + DINNER + DSTATE);
        float y = 0.f;
        #pragma unroll
        for (int n4 = 0; n4 < 32; ++n4) {
            float4 bv = Bp[n4];
            float4 cv = Cp[n4];
            st[n4 * 4 + 0] = dA * st[n4 * 4 + 0] + coef * bv.x;
            st[n4 * 4 + 1] = dA * st[n4 * 4 + 1] + coef * bv.y;
            st[n4 * 4 + 2] = dA * st[n4 * 4 + 2] + coef * bv.z;
            st[n4 * 4 + 3] = dA * st[n4 * 4 + 3] + coef * bv.w;
            y += st[n4 * 4 + 0] * cv.x;
            y += st[n4 * 4 + 1] * cv.y;
            y += st[n4 * 4 + 2] * cv.z;
            y += st[n4 * 4 + 3] * cv.w;
        }
        yf[(size_t)r * DINNER + p] = y + D0 * xv;
    }
}

// ---------------------------------------------------------------------------
// Gate + RMSNorm: g = y*silu(z); g *= rsqrt(mean(g^2)+eps)*norm_w -> bf16
// One block (256 thr) per row; each thread 4 elements.
// ---------------------------------------------------------------------------
__global__ __launch_bounds__(256) void gate_norm_kernel(
    const float* __restrict__ yf, const bf16_t* __restrict__ zx,
    const float* __restrict__ norm_w, bf16_t* __restrict__ yb)
{
    __shared__ float red[4];
    int r = blockIdx.x, tid = threadIdx.x;
    int p = tid * 4;
    float4 y = *reinterpret_cast<const float4*>(yf + (size_t)r * DINNER + p);
    bf16x4 zv = *reinterpret_cast<const bf16x4*>(zx + (size_t)r * NZX + p);
    float z0 = (float)zv[0], z1 = (float)zv[1], z2 = (float)zv[2], z3 = (float)zv[3];
    float g0 = y.x * siluf(z0);
    float g1 = y.y * siluf(z1);
    float g2 = y.z * siluf(z2);
    float g3 = y.w * siluf(z3);
    float ss = g0 * g0 + g1 * g1 + g2 * g2 + g3 * g3;
    #pragma unroll
    for (int m = 32; m >= 1; m >>= 1) ss += __shfl_xor(ss, m);
    if ((tid & 63) == 0) red[tid >> 6] = ss;
    __syncthreads();
    float tot = red[0] + red[1] + red[2] + red[3];
    float scale = rsqrtf(tot * (1.f / 1024.f) + 1e-5f);
    float4 nw = *reinterpret_cast<const float4*>(norm_w + p);
    bf16x4 o;
    o[0] = (bf16_t)(g0 * scale * nw.x);
    o[1] = (bf16_t)(g1 * scale * nw.y);
    o[2] = (bf16_t)(g2 * scale * nw.z);
    o[3] = (bf16_t)(g3 * scale * nw.w);
    *reinterpret_cast<bf16x4*>(yb + (size_t)r * DINNER + p) = o;
}

// ---------------------------------------------------------------------------
// rnn_state passthrough into the output tail
// ---------------------------------------------------------------------------
__global__ __launch_bounds__(256) void copy_f32_kernel(
    const float* __restrict__ in, float* __restrict__ out, int n)
{
    int i = blockIdx.x * 256 + threadIdx.x;
    if (i < n) out[i] = in[i];
}

// ---------------------------------------------------------------------------
extern "C" void kernel_launch(void* const* d_in, const int* in_sizes, int n_in,
                              void* d_out, int out_size, void* d_ws, size_t ws_size,
                              hipStream_t stream)
{
    const float* x        = (const float*)d_in[0];
    const float* rnn      = (const float*)d_in[1];
    const float* W_in     = (const float*)d_in[2];
    const float* conv_w   = (const float*)d_in[3];
    const float* conv_b   = (const float*)d_in[4];
    const float* dt_bias  = (const float*)d_in[5];
    const float* A_log    = (const float*)d_in[6];
    const float* Dp       = (const float*)d_in[7];
    const float* norm_w   = (const float*)d_in[8];
    const float* W_out    = (const float*)d_in[9];
    float* out = (float*)d_out;

    // workspace carve (all sizes multiples of 256B)
    char* ws = (char*)d_ws;
    bf16_t* xb     = (bf16_t*)(ws + 0);                       //  8,388,608
    bf16_t* winb   = (bf16_t*)(ws + 8388608);                 //  2,360,320
    bf16_t* woutb  = (bf16_t*)(ws + 10748928);                //  1,048,576
    bf16_t* zx     = (bf16_t*)(ws + 11797504);                // 37,748,736
    float*  dtv    = (float*) (ws + 49546240);                //     32,768
    float*  dAv    = (float*) (ws + 49579008);                //     32,768
    float*  chp    = (float*) (ws + 49611776);                //        256
    float*  xconv  = (float*) (ws + 49612032);                // 41,943,040
    float*  cstate = (float*) (ws + 91555072);                // 33,554,432
    float*  yf     = (float*) (ws + 125109504);               // 33,554,432
    bf16_t* yb     = (bf16_t*)(ws + 158663936);               // 16,777,216
    // total 175,441,152 bytes

    // 1) casts to bf16
    cast_bf16_kernel<<<(MROWS * DMODEL / 4 + 255) / 256, 256, 0, stream>>>(x, xb, MROWS * DMODEL / 4);
    cast_bf16_kernel<<<(2305 * DMODEL / 4 + 255) / 256, 256, 0, stream>>>(W_in, winb, 2305 * DMODEL / 4);
    cast_bf16_kernel<<<(DMODEL * DINNER / 4 + 255) / 256, 256, 0, stream>>>(W_out, woutb, DMODEL * DINNER / 4);

    // 2) dt column (fp32 exact) -> dtv, dAv ; chunk decay products
    dt_kernel<<<MROWS / 4, 256, 0, stream>>>(x, W_in, dt_bias, A_log, dtv, dAv);
    chunk_prod_kernel<<<1, 64, 0, stream>>>(dAv, chp);

    // 3) GEMM1: zx[8192,2304] = xb * winb^T (bf16 out)
    gemm_bf16_kernel<bf16_t><<<dim3(NZX / 128, MROWS / 128), 256, 0, stream>>>(
        xb, winb, zx, MROWS, NZX, DMODEL);

    // 4) conv + bias + silu -> xconv f32 (1280 ch)
    conv_kernel<<<MROWS * (NCONV / 4) / 256, 256, 0, stream>>>(zx, conv_w, conv_b, xconv);

    // 5) chunked scan
    scan_local_kernel<<<BATCH * NCHUNK * 4, 256, 0, stream>>>(xconv, dAv, dtv, cstate);
    scan_combine_kernel<<<BATCH * 131072 / 256, 256, 0, stream>>>(cstate, chp);
    scan_final_kernel<<<BATCH * NCHUNK * 4, 256, 0, stream>>>(xconv, cstate, dAv, dtv, Dp, yf);

    // 6) gate + RMSNorm -> yb bf16
    gate_norm_kernel<<<MROWS, 256, 0, stream>>>(yf, zx, norm_w, yb);

    // 7) GEMM2: out[8192,512] = yb * woutb^T (f32 out, directly into d_out)
    gemm_bf16_kernel<float><<<dim3(DMODEL / 128, MROWS / 128), 256, 0, stream>>>(
        yb, woutb, out, MROWS, DMODEL, DINNER);

    // 8) rnn_state passthrough
    copy_f32_kernel<<<(BATCH * DMODEL + 255) / 256, 256, 0, stream>>>(
        rnn, out + (size_t)MROWS * DMODEL, BATCH * DMODEL);
}